// Round 2
// baseline (321.350 us; speedup 1.0000x reference)
//
#include <hip/hip_runtime.h>
#include <math.h>

#define N_NODES 10000
#define E_EDGES 640000
#define EP_EDGES (E_EDGES + N_NODES)   // 650000, with self-loops
#define HEADS 8
#define NEG_SLOPE 0.2f

static __device__ __forceinline__ float leaky(float x){ return x >= 0.f ? x : NEG_SLOPE * x; }

// ---------------- CSR build ----------------
__global__ __launch_bounds__(256) void k_zero(int* __restrict__ p, int n){
  int i = blockIdx.x * 256 + threadIdx.x;
  if (i < n) p[i] = 0;
}

__global__ __launch_bounds__(256) void k_hist(const int* __restrict__ ei, int* __restrict__ deg){
  int e = blockIdx.x * 256 + threadIdx.x;
  if (e >= EP_EDGES) return;
  int dst = (e < E_EDGES) ? ei[E_EDGES + e] : (e - E_EDGES);
  atomicAdd(&deg[dst], 1);
}

// single-block exclusive scan over deg[N] -> off[0..N], cur = off (copy)
__global__ __launch_bounds__(1024) void k_scan(const int* __restrict__ deg,
                                               int* __restrict__ off,
                                               int* __restrict__ cur){
  __shared__ int wsum[16];
  int t = threadIdx.x, lane = t & 63, w = t >> 6;
  if (t == 0) off[0] = 0;
  int carry = 0;
  for (int base = 0; base < N_NODES; base += 1024){
    int i = base + t;
    int v = (i < N_NODES) ? deg[i] : 0;
    int x = v;
    #pragma unroll
    for (int o = 1; o < 64; o <<= 1){
      int y = __shfl_up(x, o);
      if (lane >= o) x += y;
    }
    if (lane == 63) wsum[w] = x;
    __syncthreads();
    int wpre = 0, tot = 0;
    #pragma unroll
    for (int j = 0; j < 16; ++j){ int s = wsum[j]; if (j < w) wpre += s; tot += s; }
    int inc = carry + wpre + x;           // inclusive prefix at i
    if (i < N_NODES){ off[i + 1] = inc; cur[i] = inc - v; }
    carry += tot;
    __syncthreads();
  }
}

__global__ __launch_bounds__(256) void k_scatter(const int* __restrict__ ei,
                                                 int* __restrict__ cur,
                                                 int* __restrict__ csr){
  int e = blockIdx.x * 256 + threadIdx.x;
  if (e >= EP_EDGES) return;
  int src, dst;
  if (e < E_EDGES){ src = ei[e]; dst = ei[E_EDGES + e]; }
  else            { src = dst = e - E_EDGES; }
  int pos = atomicAdd(&cur[dst], 1);
  csr[pos] = src;
}

// ---------------- GEMM: Y[n][c] = sum_k X[n][k] * W[k][c], K=Ncols=128 ----------------
__global__ __launch_bounds__(256) void k_gemm(const float* __restrict__ X,
                                              const float* __restrict__ W,
                                              float* __restrict__ Y, int nrows){
  __shared__ float ws[128 * 128];   // 64 KB
  __shared__ float xs[32][129];     // padded: bank-conflict-free row reads
  int t = threadIdx.x;
  {
    const float4* W4 = (const float4*)W;
    float4* ws4 = (float4*)ws;
    #pragma unroll 4
    for (int i = t; i < 4096; i += 256) ws4[i] = W4[i];
  }
  int row0 = blockIdx.x * 32;
  for (int i = t; i < 32 * 128; i += 256){
    int r = i >> 7, k = i & 127;
    float v = (row0 + r < nrows) ? X[(size_t)(row0 + r) * 128 + k] : 0.f;
    xs[r][k] = v;
  }
  __syncthreads();
  int r0 = (t >> 5) * 4;        // 8 row groups x 4 rows
  int c0 = (t & 31) * 4;        // 32 col groups x 4 cols
  float acc[4][4];
  #pragma unroll
  for (int i = 0; i < 4; ++i)
    #pragma unroll
    for (int j = 0; j < 4; ++j) acc[i][j] = 0.f;
  #pragma unroll 8
  for (int k = 0; k < 128; ++k){
    float4 wv = *(const float4*)&ws[k * 128 + c0];
    float x0 = xs[r0 + 0][k], x1 = xs[r0 + 1][k], x2 = xs[r0 + 2][k], x3 = xs[r0 + 3][k];
    acc[0][0] += x0 * wv.x; acc[0][1] += x0 * wv.y; acc[0][2] += x0 * wv.z; acc[0][3] += x0 * wv.w;
    acc[1][0] += x1 * wv.x; acc[1][1] += x1 * wv.y; acc[1][2] += x1 * wv.z; acc[1][3] += x1 * wv.w;
    acc[2][0] += x2 * wv.x; acc[2][1] += x2 * wv.y; acc[2][2] += x2 * wv.z; acc[2][3] += x2 * wv.w;
    acc[3][0] += x3 * wv.x; acc[3][1] += x3 * wv.y; acc[3][2] += x3 * wv.z; acc[3][3] += x3 * wv.w;
  }
  #pragma unroll
  for (int i = 0; i < 4; ++i){
    int r = row0 + r0 + i;
    if (r < nrows)
      *(float4*)&Y[(size_t)r * 128 + c0] = make_float4(acc[i][0], acc[i][1], acc[i][2], acc[i][3]);
  }
}

// ---------------- per-(node,head) attention scores ----------------
__global__ __launch_bounds__(256) void k_scores(const float* __restrict__ H,
    const float* __restrict__ a_src, const float* __restrict__ a_dst,
    float* __restrict__ s_src, float* __restrict__ s_dst){
  int idx = blockIdx.x * 256 + threadIdx.x;
  if (idx >= N_NODES * HEADS) return;
  int n = idx >> 3, h = idx & 7;
  const float* hp = H + (size_t)n * 128 + h * 16;
  const float* as = a_src + h * 16;
  const float* ad = a_dst + h * 16;
  float s1 = 0.f, s2 = 0.f;
  #pragma unroll
  for (int f = 0; f < 16; ++f){ float v = hp[f]; s1 += v * as[f]; s2 += v * ad[f]; }
  s_src[idx] = s1;
  s_dst[idx] = s2;
}

// ---------------- wave-per-dst-node softmax + aggregation ----------------
// MODE 0: concat heads -> out[n][128] = relu(agg + bias)
// MODE 1: mean heads   -> out[n][16]  = agg_mean + bias
template<int MODE>
__global__ __launch_bounds__(256) void k_agg(const float* __restrict__ H,
    const float* __restrict__ s_src, const float* __restrict__ s_dst,
    const int* __restrict__ csr, const int* __restrict__ off,
    const float* __restrict__ bias, float* __restrict__ out){
  int wave = (blockIdx.x * 256 + threadIdx.x) >> 6;
  int lane = threadIdx.x & 63;
  if (wave >= N_NODES) return;
  int n = __builtin_amdgcn_readfirstlane(wave);
  int beg = off[n], end = off[n + 1];

  float sdst[HEADS];
  #pragma unroll
  for (int h = 0; h < HEADS; ++h) sdst[h] = s_dst[n * 8 + h];

  // phase 1: lane-parallel online softmax stats per head
  float m[HEADS], ssum[HEADS];
  #pragma unroll
  for (int h = 0; h < HEADS; ++h){ m[h] = -1e30f; ssum[h] = 0.f; }
  for (int i = beg + lane; i < end; i += 64){
    int s = csr[i];
    const float* sp = s_src + s * 8;
    #pragma unroll
    for (int h = 0; h < HEADS; ++h){
      float l = leaky(sp[h] + sdst[h]);
      float mn = fmaxf(m[h], l);
      ssum[h] = ssum[h] * __expf(m[h] - mn) + __expf(l - mn);
      m[h] = mn;
    }
  }
  // butterfly merge across 64 lanes
  #pragma unroll
  for (int h = 0; h < HEADS; ++h){
    #pragma unroll
    for (int o = 32; o; o >>= 1){
      float mo = __shfl_xor(m[h], o);
      float so = __shfl_xor(ssum[h], o);
      float mn = fmaxf(m[h], mo);
      ssum[h] = ssum[h] * __expf(m[h] - mn) + so * __expf(mo - mn);
      m[h] = mn;
    }
  }

  // lane owns features f0=lane (head g) and f1=lane+64 (head g+4), g=lane>>4
  int g = lane >> 4;
  float mA = g == 0 ? m[0] : g == 1 ? m[1] : g == 2 ? m[2] : m[3];
  float sA = g == 0 ? ssum[0] : g == 1 ? ssum[1] : g == 2 ? ssum[2] : ssum[3];
  float dA = g == 0 ? sdst[0] : g == 1 ? sdst[1] : g == 2 ? sdst[2] : sdst[3];
  float mB = g == 0 ? m[4] : g == 1 ? m[5] : g == 2 ? m[6] : m[7];
  float sB = g == 0 ? ssum[4] : g == 1 ? ssum[5] : g == 2 ? ssum[6] : ssum[7];
  float dB = g == 0 ? sdst[4] : g == 1 ? sdst[5] : g == 2 ? sdst[6] : sdst[7];
  float invA = 1.f / sA, invB = 1.f / sB;

  // phase 2: serial over edges, coalesced h[src] row gather
  float acc0 = 0.f, acc1 = 0.f;
  #pragma unroll 2
  for (int i = beg; i < end; ++i){
    int s = csr[i];
    const float* hp = H + (size_t)s * 128;
    float sa = s_src[s * 8 + g];
    float sb = s_src[s * 8 + 4 + g];
    float a0 = __expf(leaky(sa + dA) - mA) * invA;
    float a1 = __expf(leaky(sb + dB) - mB) * invB;
    acc0 += a0 * hp[lane];
    acc1 += a1 * hp[64 + lane];
  }

  if (MODE == 0){
    float v0 = acc0 + bias[lane];
    float v1 = acc1 + bias[64 + lane];
    out[(size_t)n * 128 + lane]      = fmaxf(v0, 0.f);
    out[(size_t)n * 128 + 64 + lane] = fmaxf(v1, 0.f);
  } else {
    float s2 = acc0 + acc1;          // heads g and g+4 at feature q=lane&15
    s2 += __shfl_xor(s2, 16);
    s2 += __shfl_xor(s2, 32);
    if (lane < 16) out[(size_t)n * 16 + lane] = s2 * 0.125f + bias[lane];
  }
}

extern "C" void kernel_launch(void* const* d_in, const int* in_sizes, int n_in,
                              void* d_out, int out_size, void* d_ws, size_t ws_size,
                              hipStream_t stream){
  const float* x   = (const float*)d_in[0];
  const int*   ei  = (const int*)d_in[1];
  const float* W1  = (const float*)d_in[2];
  const float* as1 = (const float*)d_in[3];
  const float* ad1 = (const float*)d_in[4];
  const float* b1  = (const float*)d_in[5];
  const float* W2  = (const float*)d_in[6];
  const float* as2 = (const float*)d_in[7];
  const float* ad2 = (const float*)d_in[8];
  const float* b2  = (const float*)d_in[9];
  float* out = (float*)d_out;

  char* p = (char*)d_ws;
  auto alloc = [&](size_t bytes)->char*{
    char* r = p; p += (bytes + 255) & ~(size_t)255; return r;
  };
  int*   deg = (int*)  alloc((size_t)N_NODES * 4);
  int*   off = (int*)  alloc((size_t)(N_NODES + 1) * 4);
  int*   cur = (int*)  alloc((size_t)N_NODES * 4);
  int*   csr = (int*)  alloc((size_t)EP_EDGES * 4);
  float* h1  = (float*)alloc((size_t)N_NODES * 128 * 4);
  float* a1  = (float*)alloc((size_t)N_NODES * 128 * 4);
  float* ss1 = (float*)alloc((size_t)N_NODES * 8 * 4);
  float* sd1 = (float*)alloc((size_t)N_NODES * 8 * 4);
  float* ss2 = (float*)alloc((size_t)N_NODES * 8 * 4);
  float* sd2 = (float*)alloc((size_t)N_NODES * 8 * 4);
  float* h2  = h1;  // layer-1 h dead once a1 is written

  // CSR build (reused by both layers)
  k_zero<<<(N_NODES + 255) / 256, 256, 0, stream>>>(deg, N_NODES);
  k_hist<<<(EP_EDGES + 255) / 256, 256, 0, stream>>>(ei, deg);
  k_scan<<<1, 1024, 0, stream>>>(deg, off, cur);
  k_scatter<<<(EP_EDGES + 255) / 256, 256, 0, stream>>>(ei, cur, csr);

  // layer 1 (concat + bias + relu)
  k_gemm<<<(N_NODES + 31) / 32, 256, 0, stream>>>(x, W1, h1, N_NODES);
  k_scores<<<(N_NODES * HEADS + 255) / 256, 256, 0, stream>>>(h1, as1, ad1, ss1, sd1);
  k_agg<0><<<(N_NODES + 3) / 4, 256, 0, stream>>>(h1, ss1, sd1, csr, off, b1, a1);

  // layer 2 (mean + bias)
  k_gemm<<<(N_NODES + 31) / 32, 256, 0, stream>>>(a1, W2, h2, N_NODES);
  k_scores<<<(N_NODES * HEADS + 255) / 256, 256, 0, stream>>>(h2, as2, ad2, ss2, sd2);
  k_agg<1><<<(N_NODES + 3) / 4, 256, 0, stream>>>(h2, ss2, sd2, csr, off, b2, out);
}

// Round 10
// 298.857 us; speedup vs baseline: 1.0753x; 1.0753x over previous
//
#include <hip/hip_runtime.h>
#include <math.h>

#define N_NODES 10000
#define E_EDGES 640000
#define EP_EDGES (E_EDGES + N_NODES)   // 650000, with self-loops
#define HEADS 8
#define NEG_SLOPE 0.2f

static __device__ __forceinline__ float leaky(float x){ return x >= 0.f ? x : NEG_SLOPE * x; }

// ---------------- CSR build ----------------
__global__ __launch_bounds__(256) void k_hist(const int* __restrict__ ei, int* __restrict__ deg){
  int e = blockIdx.x * 256 + threadIdx.x;
  if (e >= EP_EDGES) return;
  int dst = (e < E_EDGES) ? ei[E_EDGES + e] : (e - E_EDGES);
  atomicAdd(&deg[dst], 1);
}

// single-block exclusive scan over deg[N] -> off[0..N], cur = off (copy)
__global__ __launch_bounds__(1024) void k_scan(const int* __restrict__ deg,
                                               int* __restrict__ off,
                                               int* __restrict__ cur){
  __shared__ int wsum[16];
  int t = threadIdx.x, lane = t & 63, w = t >> 6;
  if (t == 0) off[0] = 0;
  int carry = 0;
  for (int base = 0; base < N_NODES; base += 1024){
    int i = base + t;
    int v = (i < N_NODES) ? deg[i] : 0;
    int x = v;
    #pragma unroll
    for (int o = 1; o < 64; o <<= 1){
      int y = __shfl_up(x, o);
      if (lane >= o) x += y;
    }
    if (lane == 63) wsum[w] = x;
    __syncthreads();
    int wpre = 0, tot = 0;
    #pragma unroll
    for (int j = 0; j < 16; ++j){ int s = wsum[j]; if (j < w) wpre += s; tot += s; }
    int inc = carry + wpre + x;           // inclusive prefix at i
    if (i < N_NODES){ off[i + 1] = inc; cur[i] = inc - v; }
    carry += tot;
    __syncthreads();
  }
}

__global__ __launch_bounds__(256) void k_scatter(const int* __restrict__ ei,
                                                 int* __restrict__ cur,
                                                 int* __restrict__ csr){
  int e = blockIdx.x * 256 + threadIdx.x;
  if (e >= EP_EDGES) return;
  int src, dst;
  if (e < E_EDGES){ src = ei[e]; dst = ei[E_EDGES + e]; }
  else            { src = dst = e - E_EDGES; }
  int pos = atomicAdd(&cur[dst], 1);
  csr[pos] = src;
}

// ---------------- GEMM: Y[n][c] = sum_k X[n][k] * W[k][c], K=Ncols=128 ----------------
// W (64 KB) is read straight from L2 (hot across all blocks); only X staged in LDS.
__global__ __launch_bounds__(256) void k_gemm(const float* __restrict__ X,
                                              const float* __restrict__ W,
                                              float* __restrict__ Y, int nrows){
  __shared__ float xs[32][129];     // padded: bank-conflict-free row reads
  int t = threadIdx.x;
  int row0 = blockIdx.x * 32;
  const float4* X4 = (const float4*)X;
  for (int i = t; i < 1024; i += 256){
    int r = i >> 5, k4 = i & 31;
    float4 v = make_float4(0.f, 0.f, 0.f, 0.f);
    if (row0 + r < nrows) v = X4[(size_t)(row0 + r) * 32 + k4];
    xs[r][k4 * 4 + 0] = v.x; xs[r][k4 * 4 + 1] = v.y;
    xs[r][k4 * 4 + 2] = v.z; xs[r][k4 * 4 + 3] = v.w;
  }
  __syncthreads();
  int r0 = (t >> 5) * 4;        // 8 row groups x 4 rows
  int c0 = (t & 31) * 4;        // 32 col groups x 4 cols
  float acc[4][4];
  #pragma unroll
  for (int i = 0; i < 4; ++i)
    #pragma unroll
    for (int j = 0; j < 4; ++j) acc[i][j] = 0.f;
  const float4* W4 = (const float4*)W + (c0 >> 2);   // &W[k*128 + c0], k=0
  #pragma unroll 8
  for (int k = 0; k < 128; ++k){
    float4 wv = W4[(size_t)k * 32];
    float x0 = xs[r0 + 0][k], x1 = xs[r0 + 1][k], x2 = xs[r0 + 2][k], x3 = xs[r0 + 3][k];
    acc[0][0] += x0 * wv.x; acc[0][1] += x0 * wv.y; acc[0][2] += x0 * wv.z; acc[0][3] += x0 * wv.w;
    acc[1][0] += x1 * wv.x; acc[1][1] += x1 * wv.y; acc[1][2] += x1 * wv.z; acc[1][3] += x1 * wv.w;
    acc[2][0] += x2 * wv.x; acc[2][1] += x2 * wv.y; acc[2][2] += x2 * wv.z; acc[2][3] += x2 * wv.w;
    acc[3][0] += x3 * wv.x; acc[3][1] += x3 * wv.y; acc[3][2] += x3 * wv.z; acc[3][3] += x3 * wv.w;
  }
  #pragma unroll
  for (int i = 0; i < 4; ++i){
    int r = row0 + r0 + i;
    if (r < nrows)
      *(float4*)&Y[(size_t)r * 128 + c0] = make_float4(acc[i][0], acc[i][1], acc[i][2], acc[i][3]);
  }
}

// ---------------- per-(node,head) attention scores ----------------
__global__ __launch_bounds__(256) void k_scores(const float* __restrict__ H,
    const float* __restrict__ a_src, const float* __restrict__ a_dst,
    float* __restrict__ s_src, float* __restrict__ s_dst){
  int idx = blockIdx.x * 256 + threadIdx.x;
  if (idx >= N_NODES * HEADS) return;
  int n = idx >> 3, h = idx & 7;
  const float* hp = H + (size_t)n * 128 + h * 16;
  const float* as = a_src + h * 16;
  const float* ad = a_dst + h * 16;
  float s1 = 0.f, s2 = 0.f;
  #pragma unroll
  for (int f = 0; f < 16; ++f){ float v = hp[f]; s1 += v * as[f]; s2 += v * ad[f]; }
  s_src[idx] = s1;
  s_dst[idx] = s2;
}

// ---------------- 2-wave-per-dst-node softmax + aggregation ----------------
// Wave w of a node owns heads 4w..4w+3 == features [64w, 64w+64); lane owns
// feature 64w+lane (head hbase + (lane>>4)).  One exp + one FMA per edge/lane.
// MODE 0: concat heads -> out[n][128] = relu(agg + bias)
// MODE 1: mean heads   -> out[n][16]  = agg_mean + bias  (cross-wave LDS reduce)
// Grid: 5000 blocks x 256 threads = 2 nodes/block (exact for N=10000).
template<int MODE>
__global__ __launch_bounds__(256) void k_agg(const float* __restrict__ H,
    const float* __restrict__ s_src, const float* __restrict__ s_dst,
    const int* __restrict__ csr, const int* __restrict__ off,
    const float* __restrict__ bias, float* __restrict__ out){
  int t = threadIdx.x;
  int lane = t & 63;
  int wb = t >> 6;                                   // wave-in-block 0..3
  int n = __builtin_amdgcn_readfirstlane(blockIdx.x * 2 + (wb >> 1));
  int w = __builtin_amdgcn_readfirstlane(wb & 1);
  int hbase = w * 4;
  int beg = off[n], end = off[n + 1];

  float sdst[4];
  #pragma unroll
  for (int j = 0; j < 4; ++j) sdst[j] = s_dst[n * 8 + hbase + j];

  // phase 1: lane-parallel online softmax stats for this wave's 4 heads
  float m[4], ssum[4];
  #pragma unroll
  for (int j = 0; j < 4; ++j){ m[j] = -1e30f; ssum[j] = 0.f; }
  for (int i = beg + lane; i < end; i += 64){
    int s = csr[i];
    const float* sp = s_src + s * 8 + hbase;
    #pragma unroll
    for (int j = 0; j < 4; ++j){
      float l = leaky(sp[j] + sdst[j]);
      float mn = fmaxf(m[j], l);
      ssum[j] = ssum[j] * __expf(m[j] - mn) + __expf(l - mn);
      m[j] = mn;
    }
  }
  // butterfly merge across 64 lanes
  #pragma unroll
  for (int j = 0; j < 4; ++j){
    #pragma unroll
    for (int o = 32; o; o >>= 1){
      float mo = __shfl_xor(m[j], o);
      float so = __shfl_xor(ssum[j], o);
      float mn = fmaxf(m[j], mo);
      ssum[j] = ssum[j] * __expf(m[j] - mn) + so * __expf(mo - mn);
      m[j] = mn;
    }
  }

  int hl = lane >> 4;                                // head-in-wave 0..3
  float mA = hl == 0 ? m[0] : hl == 1 ? m[1] : hl == 2 ? m[2] : m[3];
  float sA = hl == 0 ? ssum[0] : hl == 1 ? ssum[1] : hl == 2 ? ssum[2] : ssum[3];
  float dA = hl == 0 ? sdst[0] : hl == 1 ? sdst[1] : hl == 2 ? sdst[2] : sdst[3];
  float inv = 1.f / sA;

  // phase 2: serial over edges; csr index is wave-uniform -> scalar loads
  const float* Hw = H + 64 * w;
  float acc = 0.f;
  #pragma unroll 4
  for (int i = beg; i < end; ++i){
    int s = csr[i];
    float sa = s_src[s * 8 + hbase + hl];
    float a = __expf(leaky(sa + dA) - mA) * inv;
    acc = fmaf(a, Hw[(size_t)s * 128 + lane], acc);
  }

  if (MODE == 0){
    int f = 64 * w + lane;
    out[(size_t)n * 128 + f] = fmaxf(acc + bias[f], 0.f);
  } else {
    // sum this wave's 4 heads at q = lane&15
    float s2 = acc;
    s2 += __shfl_xor(s2, 16);
    s2 += __shfl_xor(s2, 32);
    __shared__ float red[4][16];
    if (lane < 16) red[wb][lane] = s2;
    __syncthreads();
    if ((wb & 1) == 0 && lane < 16)
      out[(size_t)n * 16 + lane] = (red[wb][lane] + red[wb + 1][lane]) * 0.125f + bias[lane];
  }
}

extern "C" void kernel_launch(void* const* d_in, const int* in_sizes, int n_in,
                              void* d_out, int out_size, void* d_ws, size_t ws_size,
                              hipStream_t stream){
  const float* x   = (const float*)d_in[0];
  const int*   ei  = (const int*)d_in[1];
  const float* W1  = (const float*)d_in[2];
  const float* as1 = (const float*)d_in[3];
  const float* ad1 = (const float*)d_in[4];
  const float* b1  = (const float*)d_in[5];
  const float* W2  = (const float*)d_in[6];
  const float* as2 = (const float*)d_in[7];
  const float* ad2 = (const float*)d_in[8];
  const float* b2  = (const float*)d_in[9];
  float* out = (float*)d_out;

  char* p = (char*)d_ws;
  auto alloc = [&](size_t bytes)->char*{
    char* r = p; p += (bytes + 255) & ~(size_t)255; return r;
  };
  int*   deg = (int*)  alloc((size_t)N_NODES * 4);
  int*   off = (int*)  alloc((size_t)(N_NODES + 1) * 4);
  int*   cur = (int*)  alloc((size_t)N_NODES * 4);
  int*   csr = (int*)  alloc((size_t)EP_EDGES * 4);
  float* h1  = (float*)alloc((size_t)N_NODES * 128 * 4);
  float* a1  = (float*)alloc((size_t)N_NODES * 128 * 4);
  float* ss1 = (float*)alloc((size_t)N_NODES * 8 * 4);
  float* sd1 = (float*)alloc((size_t)N_NODES * 8 * 4);
  float* ss2 = (float*)alloc((size_t)N_NODES * 8 * 4);
  float* sd2 = (float*)alloc((size_t)N_NODES * 8 * 4);
  float* h2  = h1;  // layer-1 h dead once a1 is written

  // CSR build (reused by both layers); memset replaces the k_zero dispatch
  hipMemsetAsync(deg, 0, (size_t)N_NODES * 4, stream);
  k_hist<<<(EP_EDGES + 255) / 256, 256, 0, stream>>>(ei, deg);
  k_scan<<<1, 1024, 0, stream>>>(deg, off, cur);
  k_scatter<<<(EP_EDGES + 255) / 256, 256, 0, stream>>>(ei, cur, csr);

  // layer 1 (concat + bias + relu)
  k_gemm<<<(N_NODES + 31) / 32, 256, 0, stream>>>(x, W1, h1, N_NODES);
  k_scores<<<(N_NODES * HEADS + 255) / 256, 256, 0, stream>>>(h1, as1, ad1, ss1, sd1);
  k_agg<0><<<N_NODES / 2, 256, 0, stream>>>(h1, ss1, sd1, csr, off, b1, a1);

  // layer 2 (mean + bias)
  k_gemm<<<(N_NODES + 31) / 32, 256, 0, stream>>>(a1, W2, h2, N_NODES);
  k_scores<<<(N_NODES * HEADS + 255) / 256, 256, 0, stream>>>(h2, as2, ad2, ss2, sd2);
  k_agg<1><<<N_NODES / 2, 256, 0, stream>>>(h2, ss2, sd2, csr, off, b2, out);
}

// Round 14
// 280.494 us; speedup vs baseline: 1.1457x; 1.0655x over previous
//
#include <hip/hip_runtime.h>
#include <math.h>

#define N_NODES 10000
#define E_EDGES 640000
#define EP_EDGES (E_EDGES + N_NODES)   // 650000, with self-loops
#define HEADS 8
#define NEG_SLOPE 0.2f
#define CAP 160   // per-wave alpha slots; max expected degree ~97 (binomial tail + self-loop)

static __device__ __forceinline__ float leaky(float x){ return x >= 0.f ? x : NEG_SLOPE * x; }

// ---------------- CSR build ----------------
__global__ __launch_bounds__(256) void k_hist(const int* __restrict__ ei, int* __restrict__ deg){
  int e = blockIdx.x * 256 + threadIdx.x;
  if (e >= EP_EDGES) return;
  int dst = (e < E_EDGES) ? ei[E_EDGES + e] : (e - E_EDGES);
  atomicAdd(&deg[dst], 1);
}

// single-block exclusive scan over deg[N] -> off[0..N], cur = off (copy)
__global__ __launch_bounds__(1024) void k_scan(const int* __restrict__ deg,
                                               int* __restrict__ off,
                                               int* __restrict__ cur){
  __shared__ int wsum[16];
  int t = threadIdx.x, lane = t & 63, w = t >> 6;
  if (t == 0) off[0] = 0;
  int carry = 0;
  for (int base = 0; base < N_NODES; base += 1024){
    int i = base + t;
    int v = (i < N_NODES) ? deg[i] : 0;
    int x = v;
    #pragma unroll
    for (int o = 1; o < 64; o <<= 1){
      int y = __shfl_up(x, o);
      if (lane >= o) x += y;
    }
    if (lane == 63) wsum[w] = x;
    __syncthreads();
    int wpre = 0, tot = 0;
    #pragma unroll
    for (int j = 0; j < 16; ++j){ int s = wsum[j]; if (j < w) wpre += s; tot += s; }
    int inc = carry + wpre + x;           // inclusive prefix at i
    if (i < N_NODES){ off[i + 1] = inc; cur[i] = inc - v; }
    carry += tot;
    __syncthreads();
  }
}

__global__ __launch_bounds__(256) void k_scatter(const int* __restrict__ ei,
                                                 int* __restrict__ cur,
                                                 int* __restrict__ csr){
  int e = blockIdx.x * 256 + threadIdx.x;
  if (e >= EP_EDGES) return;
  int src, dst;
  if (e < E_EDGES){ src = ei[e]; dst = ei[E_EDGES + e]; }
  else            { src = dst = e - E_EDGES; }
  int pos = atomicAdd(&cur[dst], 1);
  csr[pos] = src;
}

// ---------------- GEMM: Y[n][c] = sum_k X[n][k] * W[k][c], K=Ncols=128 ----------------
// W (64 KB) is read straight from L2 (hot across all blocks); only X staged in LDS.
__global__ __launch_bounds__(256) void k_gemm(const float* __restrict__ X,
                                              const float* __restrict__ W,
                                              float* __restrict__ Y, int nrows){
  __shared__ float xs[32][129];     // padded: bank-conflict-free row reads
  int t = threadIdx.x;
  int row0 = blockIdx.x * 32;
  const float4* X4 = (const float4*)X;
  for (int i = t; i < 1024; i += 256){
    int r = i >> 5, k4 = i & 31;
    float4 v = make_float4(0.f, 0.f, 0.f, 0.f);
    if (row0 + r < nrows) v = X4[(size_t)(row0 + r) * 32 + k4];
    xs[r][k4 * 4 + 0] = v.x; xs[r][k4 * 4 + 1] = v.y;
    xs[r][k4 * 4 + 2] = v.z; xs[r][k4 * 4 + 3] = v.w;
  }
  __syncthreads();
  int r0 = (t >> 5) * 4;        // 8 row groups x 4 rows
  int c0 = (t & 31) * 4;        // 32 col groups x 4 cols
  float acc[4][4];
  #pragma unroll
  for (int i = 0; i < 4; ++i)
    #pragma unroll
    for (int j = 0; j < 4; ++j) acc[i][j] = 0.f;
  const float4* W4 = (const float4*)W + (c0 >> 2);   // &W[k*128 + c0], k=0
  #pragma unroll 8
  for (int k = 0; k < 128; ++k){
    float4 wv = W4[(size_t)k * 32];
    float x0 = xs[r0 + 0][k], x1 = xs[r0 + 1][k], x2 = xs[r0 + 2][k], x3 = xs[r0 + 3][k];
    acc[0][0] += x0 * wv.x; acc[0][1] += x0 * wv.y; acc[0][2] += x0 * wv.z; acc[0][3] += x0 * wv.w;
    acc[1][0] += x1 * wv.x; acc[1][1] += x1 * wv.y; acc[1][2] += x1 * wv.z; acc[1][3] += x1 * wv.w;
    acc[2][0] += x2 * wv.x; acc[2][1] += x2 * wv.y; acc[2][2] += x2 * wv.z; acc[2][3] += x2 * wv.w;
    acc[3][0] += x3 * wv.x; acc[3][1] += x3 * wv.y; acc[3][2] += x3 * wv.z; acc[3][3] += x3 * wv.w;
  }
  #pragma unroll
  for (int i = 0; i < 4; ++i){
    int r = row0 + r0 + i;
    if (r < nrows)
      *(float4*)&Y[(size_t)r * 128 + c0] = make_float4(acc[i][0], acc[i][1], acc[i][2], acc[i][3]);
  }
}

// ---------------- per-(node,head) attention scores ----------------
__global__ __launch_bounds__(256) void k_scores(const float* __restrict__ H,
    const float* __restrict__ a_src, const float* __restrict__ a_dst,
    float* __restrict__ s_src, float* __restrict__ s_dst){
  int idx = blockIdx.x * 256 + threadIdx.x;
  if (idx >= N_NODES * HEADS) return;
  int n = idx >> 3, h = idx & 7;
  const float* hp = H + (size_t)n * 128 + h * 16;
  const float* as = a_src + h * 16;
  const float* ad = a_dst + h * 16;
  float s1 = 0.f, s2 = 0.f;
  #pragma unroll
  for (int f = 0; f < 16; ++f){ float v = hp[f]; s1 += v * as[f]; s2 += v * ad[f]; }
  s_src[idx] = s1;
  s_dst[idx] = s2;
}

// ---------------- 2-wave-per-dst-node softmax + aggregation ----------------
// Wave w of node n owns heads 4w..4w+3 == features [64w,64w+64); lane owns
// feature 64w+lane (head hl = lane>>4).  Alpha computed ONCE per (edge,head)
// lane-parallel into LDS; the serial gather loop is pure ds_read + fma.
// MODE 0: concat -> out[n][128] = relu(agg + bias); MODE 1: mean -> out[n][16].
template<int MODE>
__global__ __launch_bounds__(256) void k_agg(const float* __restrict__ H,
    const float* __restrict__ s_src, const float* __restrict__ s_dst,
    const int* __restrict__ csr, const int* __restrict__ off,
    const float* __restrict__ bias, float* __restrict__ out){
  __shared__ float4 al4[4][CAP];                     // [wave-in-block][edge slot] = alpha for 4 heads
  int t = threadIdx.x;
  int lane = t & 63;
  int wb = t >> 6;                                   // wave-in-block 0..3
  int n = __builtin_amdgcn_readfirstlane(blockIdx.x * 2 + (wb >> 1));
  int w = __builtin_amdgcn_readfirstlane(wb & 1);
  int hbase = w * 4;
  int beg = off[n], end = off[n + 1];
  int cnt = end - beg;

  float sdst[4];
  #pragma unroll
  for (int j = 0; j < 4; ++j) sdst[j] = s_dst[n * 8 + hbase + j];

  // pass A: leaky scores into LDS (lane-parallel), track per-lane max
  float m[4];
  #pragma unroll
  for (int j = 0; j < 4; ++j) m[j] = -1e30f;
  for (int i = beg + lane, slot = lane; i < end; i += 64, slot += 64){
    int s = csr[i];
    const float* sp = s_src + s * 8 + hbase;
    float4 lv;
    lv.x = leaky(sp[0] + sdst[0]);
    lv.y = leaky(sp[1] + sdst[1]);
    lv.z = leaky(sp[2] + sdst[2]);
    lv.w = leaky(sp[3] + sdst[3]);
    m[0] = fmaxf(m[0], lv.x); m[1] = fmaxf(m[1], lv.y);
    m[2] = fmaxf(m[2], lv.z); m[3] = fmaxf(m[3], lv.w);
    if (slot < CAP) al4[wb][slot] = lv;
  }
  #pragma unroll
  for (int j = 0; j < 4; ++j){
    #pragma unroll
    for (int o = 32; o; o >>= 1) m[j] = fmaxf(m[j], __shfl_xor(m[j], o));
  }

  // pass B: exp + per-lane sum (lane-parallel), write alpha back
  float ssum[4];
  #pragma unroll
  for (int j = 0; j < 4; ++j) ssum[j] = 0.f;
  for (int i = beg + lane, slot = lane; i < end; i += 64, slot += 64){
    float4 lv;
    if (slot < CAP) lv = al4[wb][slot];
    else {
      int s = csr[i];
      const float* sp = s_src + s * 8 + hbase;
      lv.x = leaky(sp[0] + sdst[0]); lv.y = leaky(sp[1] + sdst[1]);
      lv.z = leaky(sp[2] + sdst[2]); lv.w = leaky(sp[3] + sdst[3]);
    }
    lv.x = __expf(lv.x - m[0]); lv.y = __expf(lv.y - m[1]);
    lv.z = __expf(lv.z - m[2]); lv.w = __expf(lv.w - m[3]);
    ssum[0] += lv.x; ssum[1] += lv.y; ssum[2] += lv.z; ssum[3] += lv.w;
    if (slot < CAP) al4[wb][slot] = lv;
  }
  #pragma unroll
  for (int j = 0; j < 4; ++j){
    #pragma unroll
    for (int o = 32; o; o >>= 1) ssum[j] += __shfl_xor(ssum[j], o);
  }
  float inv[4];
  #pragma unroll
  for (int j = 0; j < 4; ++j) inv[j] = 1.f / ssum[j];

  // pass C: fold 1/denom into LDS alpha (lane-parallel)
  int lim = cnt < CAP ? cnt : CAP;
  for (int slot = lane; slot < lim; slot += 64){
    float4 v = al4[wb][slot];
    v.x *= inv[0]; v.y *= inv[1]; v.z *= inv[2]; v.w *= inv[3];
    al4[wb][slot] = v;
  }

  // phase 2: serial gather-FMA; alpha via LDS broadcast, no exp
  int hl = lane >> 4;                                // head-in-wave 0..3
  const float* Hw = H + 64 * w;
  const float* alf = (const float*)&al4[wb][0];
  float acc = 0.f;
  #pragma unroll 4
  for (int j = 0; j < lim; ++j){
    int s = csr[beg + j];
    acc = fmaf(alf[j * 4 + hl], Hw[(size_t)s * 128 + lane], acc);
  }
  if (cnt > CAP){                                    // tail fallback (prob ~0)
    float mA = hl == 0 ? m[0] : hl == 1 ? m[1] : hl == 2 ? m[2] : m[3];
    float iA = hl == 0 ? inv[0] : hl == 1 ? inv[1] : hl == 2 ? inv[2] : inv[3];
    float dA = hl == 0 ? sdst[0] : hl == 1 ? sdst[1] : hl == 2 ? sdst[2] : sdst[3];
    for (int j = CAP; j < cnt; ++j){
      int s = csr[beg + j];
      float sa = s_src[s * 8 + hbase + hl];
      float a = __expf(leaky(sa + dA) - mA) * iA;
      acc = fmaf(a, Hw[(size_t)s * 128 + lane], acc);
    }
  }

  if (MODE == 0){
    int f = 64 * w + lane;
    out[(size_t)n * 128 + f] = fmaxf(acc + bias[f], 0.f);
  } else {
    // sum this wave's 4 heads at q = lane&15
    float s2 = acc;
    s2 += __shfl_xor(s2, 16);
    s2 += __shfl_xor(s2, 32);
    __shared__ float red[4][16];
    if (lane < 16) red[wb][lane] = s2;
    __syncthreads();
    if ((wb & 1) == 0 && lane < 16)
      out[(size_t)n * 16 + lane] = (red[wb][lane] + red[wb + 1][lane]) * 0.125f + bias[lane];
  }
}

extern "C" void kernel_launch(void* const* d_in, const int* in_sizes, int n_in,
                              void* d_out, int out_size, void* d_ws, size_t ws_size,
                              hipStream_t stream){
  const float* x   = (const float*)d_in[0];
  const int*   ei  = (const int*)d_in[1];
  const float* W1  = (const float*)d_in[2];
  const float* as1 = (const float*)d_in[3];
  const float* ad1 = (const float*)d_in[4];
  const float* b1  = (const float*)d_in[5];
  const float* W2  = (const float*)d_in[6];
  const float* as2 = (const float*)d_in[7];
  const float* ad2 = (const float*)d_in[8];
  const float* b2  = (const float*)d_in[9];
  float* out = (float*)d_out;

  char* p = (char*)d_ws;
  auto alloc = [&](size_t bytes)->char*{
    char* r = p; p += (bytes + 255) & ~(size_t)255; return r;
  };
  int*   deg = (int*)  alloc((size_t)N_NODES * 4);
  int*   off = (int*)  alloc((size_t)(N_NODES + 1) * 4);
  int*   cur = (int*)  alloc((size_t)N_NODES * 4);
  int*   csr = (int*)  alloc((size_t)EP_EDGES * 4);
  float* h1  = (float*)alloc((size_t)N_NODES * 128 * 4);
  float* a1  = (float*)alloc((size_t)N_NODES * 128 * 4);
  float* ss1 = (float*)alloc((size_t)N_NODES * 8 * 4);
  float* sd1 = (float*)alloc((size_t)N_NODES * 8 * 4);
  float* ss2 = (float*)alloc((size_t)N_NODES * 8 * 4);
  float* sd2 = (float*)alloc((size_t)N_NODES * 8 * 4);
  float* h2  = h1;  // layer-1 h dead once a1 is written

  // CSR build (reused by both layers); memset replaces the k_zero dispatch
  hipMemsetAsync(deg, 0, (size_t)N_NODES * 4, stream);
  k_hist<<<(EP_EDGES + 255) / 256, 256, 0, stream>>>(ei, deg);
  k_scan<<<1, 1024, 0, stream>>>(deg, off, cur);
  k_scatter<<<(EP_EDGES + 255) / 256, 256, 0, stream>>>(ei, cur, csr);

  // layer 1 (concat + bias + relu)
  k_gemm<<<(N_NODES + 31) / 32, 256, 0, stream>>>(x, W1, h1, N_NODES);
  k_scores<<<(N_NODES * HEADS + 255) / 256, 256, 0, stream>>>(h1, as1, ad1, ss1, sd1);
  k_agg<0><<<N_NODES / 2, 256, 0, stream>>>(h1, ss1, sd1, csr, off, b1, a1);

  // layer 2 (mean + bias)
  k_gemm<<<(N_NODES + 31) / 32, 256, 0, stream>>>(a1, W2, h2, N_NODES);
  k_scores<<<(N_NODES * HEADS + 255) / 256, 256, 0, stream>>>(h2, as2, ad2, ss2, sd2);
  k_agg<1><<<N_NODES / 2, 256, 0, stream>>>(h2, ss2, sd2, csr, off, b2, out);
}

// Round 15
// 266.003 us; speedup vs baseline: 1.2081x; 1.0545x over previous
//
#include <hip/hip_runtime.h>
#include <math.h>

#define N_NODES 10000
#define E_EDGES 640000
#define EP_EDGES (E_EDGES + N_NODES)   // 650000, with self-loops
#define HEADS 8
#define NEG_SLOPE 0.2f
#define CAP 160   // per-wave alpha slots; max expected degree ~97 (binomial tail + self-loop)

static __device__ __forceinline__ float leaky(float x){ return x >= 0.f ? x : NEG_SLOPE * x; }

// ---------------- CSR build ----------------
__global__ __launch_bounds__(256) void k_hist(const int* __restrict__ ei, int* __restrict__ deg){
  int e = blockIdx.x * 256 + threadIdx.x;
  if (e >= EP_EDGES) return;
  int dst = (e < E_EDGES) ? ei[E_EDGES + e] : (e - E_EDGES);
  atomicAdd(&deg[dst], 1);
}

// single-block exclusive scan over deg[N] -> off[0..N], cur = off (copy)
__global__ __launch_bounds__(1024) void k_scan(const int* __restrict__ deg,
                                               int* __restrict__ off,
                                               int* __restrict__ cur){
  __shared__ int wsum[16];
  int t = threadIdx.x, lane = t & 63, w = t >> 6;
  if (t == 0) off[0] = 0;
  int carry = 0;
  for (int base = 0; base < N_NODES; base += 1024){
    int i = base + t;
    int v = (i < N_NODES) ? deg[i] : 0;
    int x = v;
    #pragma unroll
    for (int o = 1; o < 64; o <<= 1){
      int y = __shfl_up(x, o);
      if (lane >= o) x += y;
    }
    if (lane == 63) wsum[w] = x;
    __syncthreads();
    int wpre = 0, tot = 0;
    #pragma unroll
    for (int j = 0; j < 16; ++j){ int s = wsum[j]; if (j < w) wpre += s; tot += s; }
    int inc = carry + wpre + x;           // inclusive prefix at i
    if (i < N_NODES){ off[i + 1] = inc; cur[i] = inc - v; }
    carry += tot;
    __syncthreads();
  }
}

__global__ __launch_bounds__(256) void k_scatter(const int* __restrict__ ei,
                                                 int* __restrict__ cur,
                                                 int* __restrict__ csr){
  int e = blockIdx.x * 256 + threadIdx.x;
  if (e >= EP_EDGES) return;
  int src, dst;
  if (e < E_EDGES){ src = ei[e]; dst = ei[E_EDGES + e]; }
  else            { src = dst = e - E_EDGES; }
  int pos = atomicAdd(&cur[dst], 1);
  csr[pos] = src;
}

// ---- GEMM + fused attention scores ----
// Y[n][c] = sum_k X[n][k]*W[k][c]; then per (node,head): s_src/s_dst dot-16.
// Block = 32 rows x 128 cols = 256 (node,head) pairs -> one per thread.
__global__ __launch_bounds__(256) void k_gemm(const float* __restrict__ X,
                                              const float* __restrict__ W,
                                              float* __restrict__ Y,
                                              const float* __restrict__ a_src,
                                              const float* __restrict__ a_dst,
                                              float* __restrict__ s_src,
                                              float* __restrict__ s_dst,
                                              int nrows){
  __shared__ float xs[32][129];     // padded; reused as output tile after k-loop
  int t = threadIdx.x;
  int row0 = blockIdx.x * 32;
  const float4* X4 = (const float4*)X;
  for (int i = t; i < 1024; i += 256){
    int r = i >> 5, k4 = i & 31;
    float4 v = make_float4(0.f, 0.f, 0.f, 0.f);
    if (row0 + r < nrows) v = X4[(size_t)(row0 + r) * 32 + k4];
    xs[r][k4 * 4 + 0] = v.x; xs[r][k4 * 4 + 1] = v.y;
    xs[r][k4 * 4 + 2] = v.z; xs[r][k4 * 4 + 3] = v.w;
  }
  __syncthreads();
  int r0 = (t >> 5) * 4;        // 8 row groups x 4 rows
  int c0 = (t & 31) * 4;        // 32 col groups x 4 cols
  float acc[4][4];
  #pragma unroll
  for (int i = 0; i < 4; ++i)
    #pragma unroll
    for (int j = 0; j < 4; ++j) acc[i][j] = 0.f;
  const float4* W4 = (const float4*)W + (c0 >> 2);   // &W[k*128 + c0], k=0
  #pragma unroll 8
  for (int k = 0; k < 128; ++k){
    float4 wv = W4[(size_t)k * 32];
    float x0 = xs[r0 + 0][k], x1 = xs[r0 + 1][k], x2 = xs[r0 + 2][k], x3 = xs[r0 + 3][k];
    acc[0][0] += x0 * wv.x; acc[0][1] += x0 * wv.y; acc[0][2] += x0 * wv.z; acc[0][3] += x0 * wv.w;
    acc[1][0] += x1 * wv.x; acc[1][1] += x1 * wv.y; acc[1][2] += x1 * wv.z; acc[1][3] += x1 * wv.w;
    acc[2][0] += x2 * wv.x; acc[2][1] += x2 * wv.y; acc[2][2] += x2 * wv.z; acc[2][3] += x2 * wv.w;
    acc[3][0] += x3 * wv.x; acc[3][1] += x3 * wv.y; acc[3][2] += x3 * wv.z; acc[3][3] += x3 * wv.w;
  }
  // global write + stage output tile into LDS (xs reuse, barrier-separated)
  __syncthreads();
  #pragma unroll
  for (int i = 0; i < 4; ++i){
    int r = row0 + r0 + i;
    if (r < nrows)
      *(float4*)&Y[(size_t)r * 128 + c0] = make_float4(acc[i][0], acc[i][1], acc[i][2], acc[i][3]);
    xs[r0 + i][c0 + 0] = acc[i][0]; xs[r0 + i][c0 + 1] = acc[i][1];
    xs[r0 + i][c0 + 2] = acc[i][2]; xs[r0 + i][c0 + 3] = acc[i][3];
  }
  __syncthreads();
  // fused scores: thread t -> (row r = t>>3, head h = t&7)
  int r = t >> 3, h = t & 7;
  int n = row0 + r;
  if (n < nrows){
    const float* as = a_src + h * 16;
    const float* ad = a_dst + h * 16;
    const float* yp = &xs[r][h * 16];
    float s1 = 0.f, s2 = 0.f;
    #pragma unroll
    for (int f = 0; f < 16; ++f){ float v = yp[f]; s1 += v * as[f]; s2 += v * ad[f]; }
    s_src[(size_t)n * 8 + h] = s1;       // == row0*8 + t : coalesced
    s_dst[(size_t)n * 8 + h] = s2;
  }
}

// ---------------- 2-wave-per-dst-node softmax + aggregation ----------------
// Wave w of node n owns heads 4w..4w+3 == features [64w,64w+64); lane owns
// feature 64w+lane (head hl = lane>>4).  Alpha computed ONCE per (edge,head)
// lane-parallel into LDS; the serial gather loop is pure ds_read + fma.
// MODE 0: concat -> out[n][128] = relu(agg + bias); MODE 1: mean -> out[n][16].
template<int MODE>
__global__ __launch_bounds__(256) void k_agg(const float* __restrict__ H,
    const float* __restrict__ s_src, const float* __restrict__ s_dst,
    const int* __restrict__ csr, const int* __restrict__ off,
    const float* __restrict__ bias, float* __restrict__ out){
  __shared__ float4 al4[4][CAP];                     // [wave-in-block][edge slot] = alpha for 4 heads
  int t = threadIdx.x;
  int lane = t & 63;
  int wb = t >> 6;                                   // wave-in-block 0..3
  int n = __builtin_amdgcn_readfirstlane(blockIdx.x * 2 + (wb >> 1));
  int w = __builtin_amdgcn_readfirstlane(wb & 1);
  int hbase = w * 4;
  int beg = off[n], end = off[n + 1];
  int cnt = end - beg;

  float sdst[4];
  #pragma unroll
  for (int j = 0; j < 4; ++j) sdst[j] = s_dst[n * 8 + hbase + j];

  // pass A: leaky scores into LDS (lane-parallel), track per-lane max
  float m[4];
  #pragma unroll
  for (int j = 0; j < 4; ++j) m[j] = -1e30f;
  for (int i = beg + lane, slot = lane; i < end; i += 64, slot += 64){
    int s = csr[i];
    const float* sp = s_src + s * 8 + hbase;
    float4 lv;
    lv.x = leaky(sp[0] + sdst[0]);
    lv.y = leaky(sp[1] + sdst[1]);
    lv.z = leaky(sp[2] + sdst[2]);
    lv.w = leaky(sp[3] + sdst[3]);
    m[0] = fmaxf(m[0], lv.x); m[1] = fmaxf(m[1], lv.y);
    m[2] = fmaxf(m[2], lv.z); m[3] = fmaxf(m[3], lv.w);
    if (slot < CAP) al4[wb][slot] = lv;
  }
  #pragma unroll
  for (int j = 0; j < 4; ++j){
    #pragma unroll
    for (int o = 32; o; o >>= 1) m[j] = fmaxf(m[j], __shfl_xor(m[j], o));
  }

  // pass B: exp + per-lane sum (lane-parallel), write alpha back
  float ssum[4];
  #pragma unroll
  for (int j = 0; j < 4; ++j) ssum[j] = 0.f;
  for (int i = beg + lane, slot = lane; i < end; i += 64, slot += 64){
    float4 lv;
    if (slot < CAP) lv = al4[wb][slot];
    else {
      int s = csr[i];
      const float* sp = s_src + s * 8 + hbase;
      lv.x = leaky(sp[0] + sdst[0]); lv.y = leaky(sp[1] + sdst[1]);
      lv.z = leaky(sp[2] + sdst[2]); lv.w = leaky(sp[3] + sdst[3]);
    }
    lv.x = __expf(lv.x - m[0]); lv.y = __expf(lv.y - m[1]);
    lv.z = __expf(lv.z - m[2]); lv.w = __expf(lv.w - m[3]);
    ssum[0] += lv.x; ssum[1] += lv.y; ssum[2] += lv.z; ssum[3] += lv.w;
    if (slot < CAP) al4[wb][slot] = lv;
  }
  #pragma unroll
  for (int j = 0; j < 4; ++j){
    #pragma unroll
    for (int o = 32; o; o >>= 1) ssum[j] += __shfl_xor(ssum[j], o);
  }
  float inv[4];
  #pragma unroll
  for (int j = 0; j < 4; ++j) inv[j] = 1.f / ssum[j];

  // pass C: fold 1/denom into LDS alpha (lane-parallel)
  int lim = cnt < CAP ? cnt : CAP;
  for (int slot = lane; slot < lim; slot += 64){
    float4 v = al4[wb][slot];
    v.x *= inv[0]; v.y *= inv[1]; v.z *= inv[2]; v.w *= inv[3];
    al4[wb][slot] = v;
  }

  // phase 2: serial gather-FMA; alpha via LDS broadcast, no exp
  int hl = lane >> 4;                                // head-in-wave 0..3
  const float* Hw = H + 64 * w;
  const float* alf = (const float*)&al4[wb][0];
  float acc = 0.f;
  #pragma unroll 8
  for (int j = 0; j < lim; ++j){
    int s = csr[beg + j];
    acc = fmaf(alf[j * 4 + hl], Hw[(size_t)s * 128 + lane], acc);
  }
  if (cnt > CAP){                                    // tail fallback (prob ~0)
    float mA = hl == 0 ? m[0] : hl == 1 ? m[1] : hl == 2 ? m[2] : m[3];
    float iA = hl == 0 ? inv[0] : hl == 1 ? inv[1] : hl == 2 ? inv[2] : inv[3];
    float dA = hl == 0 ? sdst[0] : hl == 1 ? sdst[1] : hl == 2 ? sdst[2] : sdst[3];
    for (int j = CAP; j < cnt; ++j){
      int s = csr[beg + j];
      float sa = s_src[s * 8 + hbase + hl];
      float a = __expf(leaky(sa + dA) - mA) * iA;
      acc = fmaf(a, Hw[(size_t)s * 128 + lane], acc);
    }
  }

  if (MODE == 0){
    int f = 64 * w + lane;
    out[(size_t)n * 128 + f] = fmaxf(acc + bias[f], 0.f);
  } else {
    // sum this wave's 4 heads at q = lane&15
    float s2 = acc;
    s2 += __shfl_xor(s2, 16);
    s2 += __shfl_xor(s2, 32);
    __shared__ float red[4][16];
    if (lane < 16) red[wb][lane] = s2;
    __syncthreads();
    if ((wb & 1) == 0 && lane < 16)
      out[(size_t)n * 16 + lane] = (red[wb][lane] + red[wb + 1][lane]) * 0.125f + bias[lane];
  }
}

extern "C" void kernel_launch(void* const* d_in, const int* in_sizes, int n_in,
                              void* d_out, int out_size, void* d_ws, size_t ws_size,
                              hipStream_t stream){
  const float* x   = (const float*)d_in[0];
  const int*   ei  = (const int*)d_in[1];
  const float* W1  = (const float*)d_in[2];
  const float* as1 = (const float*)d_in[3];
  const float* ad1 = (const float*)d_in[4];
  const float* b1  = (const float*)d_in[5];
  const float* W2  = (const float*)d_in[6];
  const float* as2 = (const float*)d_in[7];
  const float* ad2 = (const float*)d_in[8];
  const float* b2  = (const float*)d_in[9];
  float* out = (float*)d_out;

  char* p = (char*)d_ws;
  auto alloc = [&](size_t bytes)->char*{
    char* r = p; p += (bytes + 255) & ~(size_t)255; return r;
  };
  int*   deg = (int*)  alloc((size_t)N_NODES * 4);
  int*   off = (int*)  alloc((size_t)(N_NODES + 1) * 4);
  int*   cur = (int*)  alloc((size_t)N_NODES * 4);
  int*   csr = (int*)  alloc((size_t)EP_EDGES * 4);
  float* h1  = (float*)alloc((size_t)N_NODES * 128 * 4);
  float* a1  = (float*)alloc((size_t)N_NODES * 128 * 4);
  float* ss1 = (float*)alloc((size_t)N_NODES * 8 * 4);
  float* sd1 = (float*)alloc((size_t)N_NODES * 8 * 4);
  float* ss2 = (float*)alloc((size_t)N_NODES * 8 * 4);
  float* sd2 = (float*)alloc((size_t)N_NODES * 8 * 4);
  float* h2  = h1;  // layer-1 h dead once a1 is written

  // CSR build (reused by both layers); memset replaces the k_zero dispatch
  hipMemsetAsync(deg, 0, (size_t)N_NODES * 4, stream);
  k_hist<<<(EP_EDGES + 255) / 256, 256, 0, stream>>>(ei, deg);
  k_scan<<<1, 1024, 0, stream>>>(deg, off, cur);
  k_scatter<<<(EP_EDGES + 255) / 256, 256, 0, stream>>>(ei, cur, csr);

  // layer 1 (concat + bias + relu); scores fused into gemm epilogue
  k_gemm<<<(N_NODES + 31) / 32, 256, 0, stream>>>(x, W1, h1, as1, ad1, ss1, sd1, N_NODES);
  k_agg<0><<<N_NODES / 2, 256, 0, stream>>>(h1, ss1, sd1, csr, off, b1, a1);

  // layer 2 (mean + bias)
  k_gemm<<<(N_NODES + 31) / 32, 256, 0, stream>>>(a1, W2, h2, as2, ad2, ss2, sd2, N_NODES);
  k_agg<1><<<N_NODES / 2, 256, 0, stream>>>(h2, ss2, sd2, csr, off, b2, out);
}